// Round 1
// baseline (152.556 us; speedup 1.0000x reference)
//
#include <hip/hip_runtime.h>

// SortNode2Pin: for each node i, over CSR slice [starts[i], starts[i+1]) of
// flat_node2pin, output the pin p minimizing sorted_pin_map[p]; 0 if empty.
// Keys are unique (permutation), so no tie-breaking needed.

__global__ void SortNode2Pin_kernel(const int* __restrict__ starts,
                                    const int* __restrict__ n2p,
                                    const int* __restrict__ key,
                                    int* __restrict__ out,
                                    int num_nodes) {
    int i = blockIdx.x * blockDim.x + threadIdx.x;
    if (i >= num_nodes) return;
    int s = starts[i];
    int e = starts[i + 1];
    int best_pin = 0;              // empty nodes -> 0 (matches reference)
    int best_key = 0x7fffffff;
    for (int j = s; j < e; ++j) {
        int p = n2p[j];
        int k = key[p];            // random gather; table is 32MB -> L2/L3 resident
        if (k < best_key) { best_key = k; best_pin = p; }
    }
    out[i] = best_pin;
}

extern "C" void kernel_launch(void* const* d_in, const int* in_sizes, int n_in,
                              void* d_out, int out_size, void* d_ws, size_t ws_size,
                              hipStream_t stream) {
    const int* starts = (const int*)d_in[0];   // [num_nodes+1]
    const int* n2p    = (const int*)d_in[1];   // [num_pins]
    const int* key    = (const int*)d_in[2];   // [num_pins]
    int num_nodes = out_size;                  // = in_sizes[0] - 1

    int block = 256;
    int grid = (num_nodes + block - 1) / block;
    SortNode2Pin_kernel<<<grid, block, 0, stream>>>(starts, n2p, key, (int*)d_out, num_nodes);
}